// Round 11
// baseline (1039.549 us; speedup 1.0000x reference)
//
#include <hip/hip_runtime.h>
#include <hip/hip_cooperative_groups.h>
#include <math.h>

namespace cg = cooperative_groups;

#define BROWS 65536
#define DIMS 512
#define NCLS 256
#define MARGIN 0.3f
#define EPSN 1e-12f
#define PAD 16         // int padding: one counter per 64B line
#define NBLK 1024      // mega-kernel grid (4 blocks/CU co-resident)
// fallback pipeline params (R10, verified)
#define NSTRIP 64
#define SROWS 1024
#define LSPL 3
#define TSPL 8

// ======================= cooperative mega-kernel =======================
// Phases: Z zero | A hist | B scan | C scatter | D norm+segsum | E cent |
//         F nearest | G terms | H final.  8 grid.sync()s, 1 launch.
__global__ void __launch_bounds__(256, 4) kmega(
    const float* __restrict__ emb, const int* __restrict__ labels,
    float* __restrict__ out,
    int* __restrict__ hcnt, int* __restrict__ cursor,
    int* __restrict__ bases, float* __restrict__ counts,
    int* __restrict__ rowidx, float* __restrict__ invnorm,
    float* __restrict__ partials, float* __restrict__ cent,
    int* __restrict__ nearest, float* __restrict__ loss_c) {
  cg::grid_group grid = cg::this_grid();
  int t = threadIdx.x, b = blockIdx.x;
  int tid = b * 256 + t;
  int w = t >> 6, lane = t & 63;
  __shared__ float smem[4 * DIMS];  // 8 KB, aliased per phase

  // ---- Z: zero scratch ----
  if (tid < NCLS * PAD) hcnt[tid] = 0;
  else if (tid < NCLS * PAD + NCLS) loss_c[tid - NCLS * PAD] = 0.0f;
  grid.sync();

  // ---- A: padded label histogram ----
  if (tid < BROWS) atomicAdd(&hcnt[labels[tid] * PAD], 1);
  grid.sync();

  // ---- B: exclusive scan -> bases, cursor, counts (block 0) ----
  if (b == 0) {
    int c = hcnt[t * PAD];
    int* sc = (int*)smem;
    sc[t] = c;
    __syncthreads();
    int v = sc[t];
    for (int off = 1; off < NCLS; off <<= 1) {
      int add = (t >= off) ? sc[t - off] : 0;
      __syncthreads();
      sc[t] = v = v + add;
      __syncthreads();
    }
    int excl = (t == 0) ? 0 : sc[t - 1];
    bases[t] = excl;
    cursor[t * PAD] = excl;
    counts[t] = (float)c;
  }
  grid.sync();

  // ---- C: scatter rows by label (atomic order; jitter ~1e-6 ok) ----
  if (tid < BROWS) {
    int lab = labels[tid];
    int pos = atomicAdd(&cursor[lab * PAD], 1);
    rowidx[pos] = tid;
  }
  grid.sync();

  // ---- D: fused row-norm + per-class segment sum (cls, sp in 4 splits) ----
  {
    int cls = b >> 2, sp = b & 3;
    int base = bases[cls];
    int cnt = (int)counts[cls];
    int i0 = (cnt * sp) >> 2;
    int i1 = (cnt * (sp + 1)) >> 2;
    int n = i1 - i0;
    int j0 = i0 + ((n * w) >> 2);
    int j1 = i0 + ((n * (w + 1)) >> 2);
    const float4* ebase = reinterpret_cast<const float4*>(emb);
    int cq = lane * 2;
    float4 acc0 = make_float4(0.f, 0.f, 0.f, 0.f);
    float4 acc1 = make_float4(0.f, 0.f, 0.f, 0.f);
    int j = j0;
    for (; j + 4 <= j1; j += 4) {
      int r[4];
#pragma unroll
      for (int k = 0; k < 4; ++k) r[k] = rowidx[base + j + k];
      float4 a[4], bb[4];
#pragma unroll
      for (int k = 0; k < 4; ++k) {
        const float4* p = ebase + (size_t)r[k] * (DIMS / 4) + cq;
        a[k] = p[0];
        bb[k] = p[1];
      }
      float s[4];
#pragma unroll
      for (int k = 0; k < 4; ++k)
        s[k] = a[k].x*a[k].x + a[k].y*a[k].y + a[k].z*a[k].z + a[k].w*a[k].w
             + bb[k].x*bb[k].x + bb[k].y*bb[k].y + bb[k].z*bb[k].z + bb[k].w*bb[k].w;
#pragma unroll
      for (int off = 1; off < 64; off <<= 1) {
#pragma unroll
        for (int k = 0; k < 4; ++k) s[k] += __shfl_xor(s[k], off, 64);
      }
      float q[4];
#pragma unroll
      for (int k = 0; k < 4; ++k) q[k] = 1.0f / fmaxf(sqrtf(s[k]), EPSN);
      if (lane == 0) {
        invnorm[r[0]] = q[0]; invnorm[r[1]] = q[1];
        invnorm[r[2]] = q[2]; invnorm[r[3]] = q[3];
      }
#pragma unroll
      for (int k = 0; k < 4; ++k) {
        acc0.x += a[k].x * q[k]; acc0.y += a[k].y * q[k];
        acc0.z += a[k].z * q[k]; acc0.w += a[k].w * q[k];
        acc1.x += bb[k].x * q[k]; acc1.y += bb[k].y * q[k];
        acc1.z += bb[k].z * q[k]; acc1.w += bb[k].w * q[k];
      }
    }
    for (; j < j1; ++j) {
      int r0 = rowidx[base + j];
      const float4* p = ebase + (size_t)r0 * (DIMS / 4) + cq;
      float4 a = p[0], bb = p[1];
      float s = a.x*a.x + a.y*a.y + a.z*a.z + a.w*a.w
              + bb.x*bb.x + bb.y*bb.y + bb.z*bb.z + bb.w*bb.w;
#pragma unroll
      for (int off = 1; off < 64; off <<= 1) s += __shfl_xor(s, off, 64);
      float q0 = 1.0f / fmaxf(sqrtf(s), EPSN);
      if (lane == 0) invnorm[r0] = q0;
      acc0.x += a.x * q0; acc0.y += a.y * q0; acc0.z += a.z * q0; acc0.w += a.w * q0;
      acc1.x += bb.x * q0; acc1.y += bb.y * q0; acc1.z += bb.z * q0; acc1.w += bb.w * q0;
    }
    *reinterpret_cast<float4*>(&smem[w * DIMS + lane * 8]) = acc0;
    *reinterpret_cast<float4*>(&smem[w * DIMS + lane * 8 + 4]) = acc1;
    __syncthreads();
    float o0 = smem[0 * DIMS + t] + smem[1 * DIMS + t] + smem[2 * DIMS + t] + smem[3 * DIMS + t];
    float o1 = smem[0 * DIMS + t + 256] + smem[1 * DIMS + t + 256]
             + smem[2 * DIMS + t + 256] + smem[3 * DIMS + t + 256];
    float* outp = partials + ((size_t)sp * NCLS + cls) * DIMS;
    outp[t] = o0;
    outp[t + 256] = o1;
  }
  grid.sync();

  // ---- E: partials -> mean -> normalized centroid (blocks 0..255) ----
  if (b < NCLS) {
    int cls = b;
    float s0 = 0.0f, s1 = 0.0f;
#pragma unroll
    for (int sp = 0; sp < 4; ++sp) {
      const float* p = partials + ((size_t)sp * NCLS + cls) * DIMS;
      s0 += p[t];
      s1 += p[t + 256];
    }
    float cm = fmaxf(counts[cls], 1.0f);
    float m0 = s0 / cm, m1 = s1 / cm;
    float* red = smem;
    red[t] = m0 * m0 + m1 * m1;
    __syncthreads();
    for (int off = 128; off > 0; off >>= 1) {
      if (t < off) red[t] += red[t + off];
      __syncthreads();
    }
    float inv = 1.0f / fmaxf(sqrtf(red[0]), EPSN);
    cent[(size_t)cls * DIMS + t] = m0 * inv;
    cent[(size_t)cls * DIMS + t + 256] = m1 * inv;
  }
  grid.sync();

  // ---- F: nearest-centroid argmin (blocks 0..255; lexicographic ties) ----
  if (b < NCLS) {
    int i = b, j = t;
    float* ci = smem;                       // 512 floats
    float* sd = smem + DIMS;                // 256
    int* si = (int*)(smem + DIMS + 256);    // 256
    ci[j] = cent[(size_t)i * DIMS + j];
    ci[j + 256] = cent[(size_t)i * DIMS + j + 256];
    __syncthreads();
    const float4* cj = reinterpret_cast<const float4*>(cent + (size_t)j * DIMS);
    float dot = 0.0f;
#pragma unroll 8
    for (int k = 0; k < DIMS / 4; ++k) {
      float4 v = cj[k];
      dot += v.x * ci[4*k] + v.y * ci[4*k+1] + v.z * ci[4*k+2] + v.w * ci[4*k+3];
    }
    float dist = sqrtf(fmaxf(2.0f - 2.0f * dot, 0.0f));
    bool valid = (j != i) && (counts[j] > 0.0f);
    sd[j] = valid ? dist : INFINITY;
    si[j] = j;
    __syncthreads();
    for (int off = 128; off > 0; off >>= 1) {
      if (j < off) {
        float o = sd[j + off]; int oi = si[j + off];
        if (o < sd[j] || (o == sd[j] && oi < si[j])) { sd[j] = o; si[j] = oi; }
      }
      __syncthreads();
    }
    if (j == 0) nearest[i] = si[0];
  }
  grid.sync();

  // ---- G: triplet terms (cls, sp in 4 splits); block sum -> loss_c ----
  {
    int cls = b >> 2, sp = b & 3;
    int base = bases[cls];
    int cnt = (int)counts[cls];
    int ng = nearest[cls];
    int cq = lane * 2;
    const float4* pp = reinterpret_cast<const float4*>(cent + (size_t)cls * DIMS) + cq;
    const float4* pn = reinterpret_cast<const float4*>(cent + (size_t)ng * DIMS) + cq;
    float4 P0 = pp[0], P1 = pp[1], N0 = pn[0], N1 = pn[1];
    float4 d0 = make_float4(N0.x - P0.x, N0.y - P0.y, N0.z - P0.z, N0.w - P0.w);
    float4 d1 = make_float4(N1.x - P1.x, N1.y - P1.y, N1.z - P1.z, N1.w - P1.w);
    int i0 = (cnt * sp) >> 2;
    int i1 = (cnt * (sp + 1)) >> 2;
    int n = i1 - i0;
    int j0 = i0 + ((n * w) >> 2);
    int j1 = i0 + ((n * (w + 1)) >> 2);
    const float4* ebase = reinterpret_cast<const float4*>(emb);
    float tsum = 0.0f;
    int j = j0;
    for (; j + 4 <= j1; j += 4) {
      int r[4];
#pragma unroll
      for (int k = 0; k < 4; ++k) r[k] = rowidx[base + j + k];
      float inv[4];
#pragma unroll
      for (int k = 0; k < 4; ++k) inv[k] = invnorm[r[k]];
      float4 a[4], bb[4];
#pragma unroll
      for (int k = 0; k < 4; ++k) {
        const float4* p = ebase + (size_t)r[k] * (DIMS / 4) + cq;
        a[k] = p[0];
        bb[k] = p[1];
      }
      float s[4];
#pragma unroll
      for (int k = 0; k < 4; ++k)
        s[k] = a[k].x*d0.x + a[k].y*d0.y + a[k].z*d0.z + a[k].w*d0.w
             + bb[k].x*d1.x + bb[k].y*d1.y + bb[k].z*d1.z + bb[k].w*d1.w;
#pragma unroll
      for (int off = 1; off < 64; off <<= 1) {
#pragma unroll
        for (int k = 0; k < 4; ++k) s[k] += __shfl_xor(s[k], off, 64);
      }
#pragma unroll
      for (int k = 0; k < 4; ++k) tsum += fmaxf(s[k] * inv[k] + MARGIN, 0.0f);
    }
    for (; j < j1; ++j) {
      int r0 = rowidx[base + j];
      float inv0 = invnorm[r0];
      const float4* p = ebase + (size_t)r0 * (DIMS / 4) + cq;
      float4 a = p[0], bb = p[1];
      float s = a.x*d0.x + a.y*d0.y + a.z*d0.z + a.w*d0.w
              + bb.x*d1.x + bb.y*d1.y + bb.z*d1.z + bb.w*d1.w;
#pragma unroll
      for (int off = 1; off < 64; off <<= 1) s += __shfl_xor(s, off, 64);
      tsum += fmaxf(s * inv0 + MARGIN, 0.0f);
    }
    __syncthreads();  // smem reuse guard
    if (lane == 0) smem[w] = tsum;
    __syncthreads();
    if (t == 0) atomicAdd(&loss_c[cls], smem[0] + smem[1] + smem[2] + smem[3]);
  }
  grid.sync();

  // ---- H: final present-masked mean of per-class means (block 0) ----
  if (b == 0) {
    float cnt = counts[t];
    bool present = cnt > 0.0f;
    float v = present ? loss_c[t] / fmaxf(cnt, 1.0f) : 0.0f;
    float np = present ? 1.0f : 0.0f;
    float* sv = smem;
    float* sp_ = smem + 256;
    sv[t] = v; sp_[t] = np;
    __syncthreads();
    for (int off = 128; off > 0; off >>= 1) {
      if (t < off) { sv[t] += sv[t + off]; sp_[t] += sp_[t + off]; }
      __syncthreads();
    }
    if (t == 0) out[0] = sv[0] / fmaxf(sp_[0], 1.0f);
  }
}

// ======================= fallback pipeline (R10, verified) =======================
__global__ void __launch_bounds__(256) khist2(const int* __restrict__ labels,
                                              int* __restrict__ hist) {
  __shared__ int h[NCLS];
  int t = threadIdx.x, s = blockIdx.x;
  h[t] = 0;
  __syncthreads();
  int base = s * SROWS + t;
#pragma unroll
  for (int k = 0; k < SROWS / 256; ++k) atomicAdd(&h[labels[base + k * 256]], 1);
  __syncthreads();
  hist[s * NCLS + t] = h[t];
}

__global__ void __launch_bounds__(256) kscatter2(const int* __restrict__ labels,
                                                 const int* __restrict__ hist,
                                                 int* __restrict__ bases,
                                                 float* __restrict__ counts,
                                                 int* __restrict__ rowidx) {
  int t = threadIdx.x, s = blockIdx.x;
  int run = 0, myoff = 0;
  for (int s2 = 0; s2 < NSTRIP; ++s2) {
    int h = hist[s2 * NCLS + t];
    if (s2 < s) myoff += h;
    run += h;
  }
  __shared__ int sc[NCLS];
  sc[t] = run;
  __syncthreads();
  int v = sc[t];
  for (int off = 1; off < NCLS; off <<= 1) {
    int add = (t >= off) ? sc[t - off] : 0;
    __syncthreads();
    sc[t] = v = v + add;
    __syncthreads();
  }
  int excl = (t == 0) ? 0 : sc[t - 1];
  if (s == 0) {
    bases[t] = excl;
    counts[t] = (float)run;
  }
  __shared__ int loff[NCLS];
  __shared__ int cur[NCLS];
  loff[t] = excl + myoff;
  cur[t] = 0;
  __syncthreads();
  int rbase = s * SROWS + t;
#pragma unroll
  for (int k = 0; k < SROWS / 256; ++k) {
    int r = rbase + k * 256;
    int lab = labels[r];
    int lpos = atomicAdd(&cur[lab], 1);
    rowidx[loff[lab] + lpos] = r;
  }
}

__global__ void __launch_bounds__(256) ksumn(const float* __restrict__ emb,
                                             const int* __restrict__ rowidx,
                                             const int* __restrict__ bases,
                                             const float* __restrict__ counts,
                                             float* __restrict__ invnorm,
                                             float* __restrict__ partials) {
  int cls = blockIdx.x >> LSPL;
  int sp = blockIdx.x & ((1 << LSPL) - 1);
  int t = threadIdx.x, w = t >> 6, lane = t & 63;
  int base = bases[cls];
  int cnt = (int)counts[cls];
  int i0 = (cnt * sp) >> LSPL;
  int i1 = (cnt * (sp + 1)) >> LSPL;
  int n = i1 - i0;
  int j0 = i0 + ((n * w) >> 2);
  int j1 = i0 + ((n * (w + 1)) >> 2);
  const float4* ebase = reinterpret_cast<const float4*>(emb);
  int cq = lane * 2;
  float4 acc0 = make_float4(0.f, 0.f, 0.f, 0.f);
  float4 acc1 = make_float4(0.f, 0.f, 0.f, 0.f);
  int j = j0;
  for (; j + 4 <= j1; j += 4) {
    int r[4];
#pragma unroll
    for (int k = 0; k < 4; ++k) r[k] = rowidx[base + j + k];
    float4 a[4], b[4];
#pragma unroll
    for (int k = 0; k < 4; ++k) {
      const float4* p = ebase + (size_t)r[k] * (DIMS / 4) + cq;
      a[k] = p[0];
      b[k] = p[1];
    }
    float s[4];
#pragma unroll
    for (int k = 0; k < 4; ++k)
      s[k] = a[k].x*a[k].x + a[k].y*a[k].y + a[k].z*a[k].z + a[k].w*a[k].w
           + b[k].x*b[k].x + b[k].y*b[k].y + b[k].z*b[k].z + b[k].w*b[k].w;
#pragma unroll
    for (int off = 1; off < 64; off <<= 1) {
#pragma unroll
      for (int k = 0; k < 4; ++k) s[k] += __shfl_xor(s[k], off, 64);
    }
    float q[4];
#pragma unroll
    for (int k = 0; k < 4; ++k) q[k] = 1.0f / fmaxf(sqrtf(s[k]), EPSN);
    if (lane == 0) {
      invnorm[r[0]] = q[0]; invnorm[r[1]] = q[1];
      invnorm[r[2]] = q[2]; invnorm[r[3]] = q[3];
    }
#pragma unroll
    for (int k = 0; k < 4; ++k) {
      acc0.x += a[k].x * q[k]; acc0.y += a[k].y * q[k];
      acc0.z += a[k].z * q[k]; acc0.w += a[k].w * q[k];
      acc1.x += b[k].x * q[k]; acc1.y += b[k].y * q[k];
      acc1.z += b[k].z * q[k]; acc1.w += b[k].w * q[k];
    }
  }
  for (; j < j1; ++j) {
    int r0 = rowidx[base + j];
    const float4* p = ebase + (size_t)r0 * (DIMS / 4) + cq;
    float4 a = p[0], b = p[1];
    float s = a.x*a.x + a.y*a.y + a.z*a.z + a.w*a.w
            + b.x*b.x + b.y*b.y + b.z*b.z + b.w*b.w;
#pragma unroll
    for (int off = 1; off < 64; off <<= 1) s += __shfl_xor(s, off, 64);
    float q0 = 1.0f / fmaxf(sqrtf(s), EPSN);
    if (lane == 0) invnorm[r0] = q0;
    acc0.x += a.x * q0; acc0.y += a.y * q0; acc0.z += a.z * q0; acc0.w += a.w * q0;
    acc1.x += b.x * q0; acc1.y += b.y * q0; acc1.z += b.z * q0; acc1.w += b.w * q0;
  }
  __shared__ float lds[4][DIMS];
  *reinterpret_cast<float4*>(&lds[w][lane * 8]) = acc0;
  *reinterpret_cast<float4*>(&lds[w][lane * 8 + 4]) = acc1;
  __syncthreads();
  float o0 = lds[0][t] + lds[1][t] + lds[2][t] + lds[3][t];
  float o1 = lds[0][t + 256] + lds[1][t + 256] + lds[2][t + 256] + lds[3][t + 256];
  float* outp = partials + ((size_t)sp * NCLS + cls) * DIMS;
  outp[t] = o0;
  outp[t + 256] = o1;
}

__global__ void __launch_bounds__(256) kcent(const float* __restrict__ partials,
                                             const float* __restrict__ counts,
                                             float* __restrict__ cent) {
  int cls = blockIdx.x, t = threadIdx.x;
  float s0 = 0.0f, s1 = 0.0f;
#pragma unroll
  for (int sp = 0; sp < (1 << LSPL); ++sp) {
    const float* p = partials + ((size_t)sp * NCLS + cls) * DIMS;
    s0 += p[t];
    s1 += p[t + 256];
  }
  float cm = fmaxf(counts[cls], 1.0f);
  float m0 = s0 / cm, m1 = s1 / cm;
  __shared__ float red[256];
  red[t] = m0 * m0 + m1 * m1;
  __syncthreads();
  for (int off = 128; off > 0; off >>= 1) {
    if (t < off) red[t] += red[t + off];
    __syncthreads();
  }
  float inv = 1.0f / fmaxf(sqrtf(red[0]), EPSN);
  cent[(size_t)cls * DIMS + t] = m0 * inv;
  cent[(size_t)cls * DIMS + t + 256] = m1 * inv;
}

__global__ void __launch_bounds__(256) knearest(const float* __restrict__ cent,
                                                const float* __restrict__ counts,
                                                int* __restrict__ nearest) {
  int i = blockIdx.x, j = threadIdx.x;
  __shared__ float ci[DIMS];
  ci[j] = cent[(size_t)i * DIMS + j];
  ci[j + 256] = cent[(size_t)i * DIMS + j + 256];
  __syncthreads();
  const float4* cj = reinterpret_cast<const float4*>(cent + (size_t)j * DIMS);
  float dot = 0.0f;
#pragma unroll 8
  for (int k = 0; k < DIMS / 4; ++k) {
    float4 v = cj[k];
    dot += v.x * ci[4*k] + v.y * ci[4*k+1] + v.z * ci[4*k+2] + v.w * ci[4*k+3];
  }
  float dist = sqrtf(fmaxf(2.0f - 2.0f * dot, 0.0f));
  bool valid = (j != i) && (counts[j] > 0.0f);
  float dv = valid ? dist : INFINITY;
  __shared__ float sd[256];
  __shared__ int si[256];
  sd[j] = dv; si[j] = j;
  __syncthreads();
  for (int off = 128; off > 0; off >>= 1) {
    if (j < off) {
      float o = sd[j + off]; int oi = si[j + off];
      if (o < sd[j] || (o == sd[j] && oi < si[j])) { sd[j] = o; si[j] = oi; }
    }
    __syncthreads();
  }
  if (j == 0) nearest[i] = si[0];
}

__global__ void __launch_bounds__(256) kterm2(const float* __restrict__ emb,
                                              const float* __restrict__ invnorm,
                                              const int* __restrict__ rowidx,
                                              const int* __restrict__ bases,
                                              const float* __restrict__ counts,
                                              const float* __restrict__ cent,
                                              const int* __restrict__ nearest,
                                              float* __restrict__ tsums) {
  int cls = blockIdx.x >> 3;
  int sp = blockIdx.x & (TSPL - 1);
  int t = threadIdx.x, w = t >> 6, lane = t & 63;
  int base = bases[cls];
  int cnt = (int)counts[cls];
  int ng = nearest[cls];
  int cq = lane * 2;
  const float4* pp = reinterpret_cast<const float4*>(cent + (size_t)cls * DIMS) + cq;
  const float4* pn = reinterpret_cast<const float4*>(cent + (size_t)ng * DIMS) + cq;
  float4 P0 = pp[0], P1 = pp[1], N0 = pn[0], N1 = pn[1];
  float4 d0 = make_float4(N0.x - P0.x, N0.y - P0.y, N0.z - P0.z, N0.w - P0.w);
  float4 d1 = make_float4(N1.x - P1.x, N1.y - P1.y, N1.z - P1.z, N1.w - P1.w);
  int i0 = (cnt * sp) / TSPL;
  int i1 = (cnt * (sp + 1)) / TSPL;
  int n = i1 - i0;
  int j0 = i0 + ((n * w) >> 2);
  int j1 = i0 + ((n * (w + 1)) >> 2);
  const float4* ebase = reinterpret_cast<const float4*>(emb);
  float tsum = 0.0f;
  int j = j0;
  for (; j + 4 <= j1; j += 4) {
    int r[4];
#pragma unroll
    for (int k = 0; k < 4; ++k) r[k] = rowidx[base + j + k];
    float inv[4];
#pragma unroll
    for (int k = 0; k < 4; ++k) inv[k] = invnorm[r[k]];
    float4 a[4], b[4];
#pragma unroll
    for (int k = 0; k < 4; ++k) {
      const float4* p = ebase + (size_t)r[k] * (DIMS / 4) + cq;
      a[k] = p[0];
      b[k] = p[1];
    }
    float s[4];
#pragma unroll
    for (int k = 0; k < 4; ++k)
      s[k] = a[k].x*d0.x + a[k].y*d0.y + a[k].z*d0.z + a[k].w*d0.w
           + b[k].x*d1.x + b[k].y*d1.y + b[k].z*d1.z + b[k].w*d1.w;
#pragma unroll
    for (int off = 1; off < 64; off <<= 1) {
#pragma unroll
      for (int k = 0; k < 4; ++k) s[k] += __shfl_xor(s[k], off, 64);
    }
#pragma unroll
    for (int k = 0; k < 4; ++k) tsum += fmaxf(s[k] * inv[k] + MARGIN, 0.0f);
  }
  for (; j < j1; ++j) {
    int r0 = rowidx[base + j];
    float inv0 = invnorm[r0];
    const float4* p = ebase + (size_t)r0 * (DIMS / 4) + cq;
    float4 a = p[0], b = p[1];
    float s = a.x*d0.x + a.y*d0.y + a.z*d0.z + a.w*d0.w
            + b.x*d1.x + b.y*d1.y + b.z*d1.z + b.w*d1.w;
#pragma unroll
    for (int off = 1; off < 64; off <<= 1) s += __shfl_xor(s, off, 64);
    tsum += fmaxf(s * inv0 + MARGIN, 0.0f);
  }
  __shared__ float sred[4];
  if (lane == 0) sred[w] = tsum;
  __syncthreads();
  if (t == 0) tsums[blockIdx.x] = sred[0] + sred[1] + sred[2] + sred[3];
}

__global__ void __launch_bounds__(256) kfinal(const float* __restrict__ counts,
                                              const float* __restrict__ tsums,
                                              float* __restrict__ out) {
  int t = threadIdx.x;
  float cnt = counts[t];
  bool present = cnt > 0.0f;
  float ls = 0.0f;
#pragma unroll
  for (int k = 0; k < TSPL; ++k) ls += tsums[t * TSPL + k];
  float v = present ? ls / fmaxf(cnt, 1.0f) : 0.0f;
  float np = present ? 1.0f : 0.0f;
  __shared__ float sv[256], sp[256];
  sv[t] = v; sp[t] = np;
  __syncthreads();
  for (int off = 128; off > 0; off >>= 1) {
    if (t < off) { sv[t] += sv[t + off]; sp[t] += sp[t + off]; }
    __syncthreads();
  }
  if (t == 0) out[0] = sv[0] / fmaxf(sp[0], 1.0f);
}

extern "C" void kernel_launch(void* const* d_in, const int* in_sizes, int n_in,
                              void* d_out, int out_size, void* d_ws, size_t ws_size,
                              hipStream_t stream) {
  const float* emb = (const float*)d_in[0];
  const int* labels = (const int*)d_in[1];
  float* out = (float*)d_out;

  char* ws = (char*)d_ws;
  size_t off = 0;
  auto alloc = [&](size_t bytes) {
    char* p = ws + off;
    off += (bytes + 255) & ~(size_t)255;
    return p;
  };
  // shared buffers (mega + fallback)
  int*   hcnt    = (int*)alloc((size_t)NCLS * PAD * 4);               // 16 KB
  int*   cursor  = (int*)alloc((size_t)NCLS * PAD * 4);               // 16 KB
  int*   bases   = (int*)alloc((size_t)NCLS * 4);
  float* counts  = (float*)alloc((size_t)NCLS * 4);
  int*   rowidx  = (int*)alloc((size_t)BROWS * 4);                    // 256 KB
  float* invnorm = (float*)alloc((size_t)BROWS * 4);                  // 256 KB
  float* partials= (float*)alloc((size_t)8 * NCLS * DIMS * 4);        // 4 MB (max of both paths)
  float* cent    = (float*)alloc((size_t)NCLS * DIMS * 4);            // 512 KB
  int*   nearest = (int*)alloc((size_t)NCLS * 4);
  float* loss_c  = (float*)alloc((size_t)NCLS * 4);
  // fallback-only
  int*   hist    = (int*)alloc((size_t)NSTRIP * NCLS * 4);            // 64 KB
  float* tsums   = (float*)alloc((size_t)NCLS * TSPL * 4);            // 8 KB

  void* args[] = {(void*)&emb, (void*)&labels, (void*)&out,
                  (void*)&hcnt, (void*)&cursor, (void*)&bases, (void*)&counts,
                  (void*)&rowidx, (void*)&invnorm, (void*)&partials,
                  (void*)&cent, (void*)&nearest, (void*)&loss_c};
  hipError_t err = hipLaunchCooperativeKernel((const void*)kmega,
                                              dim3(NBLK), dim3(256),
                                              args, 0, stream);
  if (err != hipSuccess) {
    // fallback: verified 7-kernel pipeline (R10)
    khist2<<<NSTRIP, 256, 0, stream>>>(labels, hist);
    kscatter2<<<NSTRIP, 256, 0, stream>>>(labels, hist, bases, counts, rowidx);
    ksumn<<<NCLS << LSPL, 256, 0, stream>>>(emb, rowidx, bases, counts, invnorm, partials);
    kcent<<<NCLS, 256, 0, stream>>>(partials, counts, cent);
    knearest<<<NCLS, 256, 0, stream>>>(cent, counts, nearest);
    kterm2<<<NCLS * TSPL, 256, 0, stream>>>(emb, invnorm, rowidx, bases, counts,
                                            cent, nearest, tsums);
    kfinal<<<1, 256, 0, stream>>>(counts, tsums, out);
  }
}

// Round 12
// 902.632 us; speedup vs baseline: 1.1517x; 1.1517x over previous
//
#include <hip/hip_runtime.h>
#include <math.h>

#define BROWS 65536
#define DIMS 512
#define NCLS 256
#define MARGIN 0.3f
#define EPSN 1e-12f
#define NSTRIP 64      // 64 strips x 1024 rows
#define SROWS 1024
#define LSPL 3         // 8 splits/class in ksumn2
#define TSPL 8         // 8 splits/class in kterm3

// K1: fused per-strip histogram + deterministic scatter.
// 64 blocks (all co-resident on 256 CUs) sync via device-atomic barrier.
__global__ void __launch_bounds__(256) kscatter3(const int* __restrict__ labels,
                                                 int* __restrict__ hist,
                                                 int* __restrict__ done,
                                                 int* __restrict__ bases,
                                                 float* __restrict__ counts,
                                                 int* __restrict__ rowidx) {
  int t = threadIdx.x, s = blockIdx.x;  // t = class
  // phase 1: per-strip LDS histogram
  __shared__ int h[NCLS];
  h[t] = 0;
  __syncthreads();
  int rbase = s * SROWS + t;
#pragma unroll
  for (int k = 0; k < SROWS / 256; ++k) atomicAdd(&h[labels[rbase + k * 256]], 1);
  __syncthreads();
  hist[s * NCLS + t] = h[t];
  __threadfence();                       // release hist writes
  // barrier: 64 blocks, lane-0 spin on device atomic
  if (t == 0) {
    atomicAdd(done, 1);
    while (atomicAdd(done, 0) < NSTRIP) { }
  }
  __syncthreads();
  __threadfence();                       // acquire all hists
  // phase 2: class bases (scan) + my strip offset
  int run = 0, myoff = 0;
  for (int s2 = 0; s2 < NSTRIP; ++s2) {
    int hv = hist[s2 * NCLS + t];        // coalesced across t
    if (s2 < s) myoff += hv;
    run += hv;
  }
  __shared__ int sc[NCLS];
  sc[t] = run;
  __syncthreads();
  int v = sc[t];
  for (int off = 1; off < NCLS; off <<= 1) {
    int add = (t >= off) ? sc[t - off] : 0;
    __syncthreads();
    sc[t] = v = v + add;
    __syncthreads();
  }
  int excl = (t == 0) ? 0 : sc[t - 1];
  if (s == 0) {
    bases[t] = excl;
    counts[t] = (float)run;
  }
  __shared__ int loff[NCLS];
  __shared__ int cur[NCLS];
  loff[t] = excl + myoff;
  cur[t] = 0;
  __syncthreads();
  // phase 3: deterministic scatter via LDS cursors
#pragma unroll
  for (int k = 0; k < SROWS / 256; ++k) {
    int r = rbase + k * 256;
    int lab = labels[r];
    int lpos = atomicAdd(&cur[lab], 1);
    rowidx[loff[lab] + lpos] = r;
  }
}

// K2: fused row-norm + per-class segment sum; the LAST of the 8 blocks of a
// class additionally reduces partials -> mean -> normalized centroid inline.
__global__ void __launch_bounds__(256) ksumn2(const float* __restrict__ emb,
                                              const int* __restrict__ rowidx,
                                              const int* __restrict__ bases,
                                              const float* __restrict__ counts,
                                              float* __restrict__ invnorm,
                                              float* __restrict__ partials,
                                              int* __restrict__ ccnt,
                                              float* __restrict__ cent) {
  int cls = blockIdx.x >> LSPL;
  int sp = blockIdx.x & ((1 << LSPL) - 1);
  int t = threadIdx.x, w = t >> 6, lane = t & 63;
  int base = bases[cls];
  int cnt = (int)counts[cls];
  int i0 = (cnt * sp) >> LSPL;
  int i1 = (cnt * (sp + 1)) >> LSPL;
  int n = i1 - i0;
  int j0 = i0 + ((n * w) >> 2);
  int j1 = i0 + ((n * (w + 1)) >> 2);
  const float4* ebase = reinterpret_cast<const float4*>(emb);
  int cq = lane * 2;  // float4 index: cols [lane*8, lane*8+8)
  float4 acc0 = make_float4(0.f, 0.f, 0.f, 0.f);
  float4 acc1 = make_float4(0.f, 0.f, 0.f, 0.f);
  int j = j0;
  for (; j + 4 <= j1; j += 4) {
    int r[4];
#pragma unroll
    for (int k = 0; k < 4; ++k) r[k] = rowidx[base + j + k];
    float4 a[4], b[4];
#pragma unroll
    for (int k = 0; k < 4; ++k) {
      const float4* p = ebase + (size_t)r[k] * (DIMS / 4) + cq;
      a[k] = p[0];
      b[k] = p[1];
    }
    float s[4];
#pragma unroll
    for (int k = 0; k < 4; ++k)
      s[k] = a[k].x*a[k].x + a[k].y*a[k].y + a[k].z*a[k].z + a[k].w*a[k].w
           + b[k].x*b[k].x + b[k].y*b[k].y + b[k].z*b[k].z + b[k].w*b[k].w;
#pragma unroll
    for (int off = 1; off < 64; off <<= 1) {
#pragma unroll
      for (int k = 0; k < 4; ++k) s[k] += __shfl_xor(s[k], off, 64);
    }
    float q[4];
#pragma unroll
    for (int k = 0; k < 4; ++k) q[k] = 1.0f / fmaxf(sqrtf(s[k]), EPSN);
    if (lane == 0) {
      invnorm[r[0]] = q[0]; invnorm[r[1]] = q[1];
      invnorm[r[2]] = q[2]; invnorm[r[3]] = q[3];
    }
#pragma unroll
    for (int k = 0; k < 4; ++k) {
      acc0.x += a[k].x * q[k]; acc0.y += a[k].y * q[k];
      acc0.z += a[k].z * q[k]; acc0.w += a[k].w * q[k];
      acc1.x += b[k].x * q[k]; acc1.y += b[k].y * q[k];
      acc1.z += b[k].z * q[k]; acc1.w += b[k].w * q[k];
    }
  }
  for (; j < j1; ++j) {
    int r0 = rowidx[base + j];
    const float4* p = ebase + (size_t)r0 * (DIMS / 4) + cq;
    float4 a = p[0], b = p[1];
    float s = a.x*a.x + a.y*a.y + a.z*a.z + a.w*a.w
            + b.x*b.x + b.y*b.y + b.z*b.z + b.w*b.w;
#pragma unroll
    for (int off = 1; off < 64; off <<= 1) s += __shfl_xor(s, off, 64);
    float q0 = 1.0f / fmaxf(sqrtf(s), EPSN);
    if (lane == 0) invnorm[r0] = q0;
    acc0.x += a.x * q0; acc0.y += a.y * q0; acc0.z += a.z * q0; acc0.w += a.w * q0;
    acc1.x += b.x * q0; acc1.y += b.y * q0; acc1.z += b.z * q0; acc1.w += b.w * q0;
  }
  __shared__ float lds[4][DIMS];
  *reinterpret_cast<float4*>(&lds[w][lane * 8]) = acc0;
  *reinterpret_cast<float4*>(&lds[w][lane * 8 + 4]) = acc1;
  __syncthreads();
  float o0 = lds[0][t] + lds[1][t] + lds[2][t] + lds[3][t];
  float o1 = lds[0][t + 256] + lds[1][t + 256] + lds[2][t + 256] + lds[3][t + 256];
  float* outp = partials + ((size_t)sp * NCLS + cls) * DIMS;
  outp[t] = o0;
  outp[t + 256] = o1;
  // ---- last block of this class: inline centroid reduce (deterministic) ----
  __threadfence();                       // release partials
  __shared__ int lastflag;
  if (t == 0) lastflag = (atomicAdd(&ccnt[cls], 1) == (1 << LSPL) - 1) ? 1 : 0;
  __syncthreads();
  if (lastflag) {
    __threadfence();                     // acquire all 8 partials
    float s0 = 0.0f, s1 = 0.0f;
#pragma unroll
    for (int spp = 0; spp < (1 << LSPL); ++spp) {
      const float* p = partials + ((size_t)spp * NCLS + cls) * DIMS;
      s0 += p[t];
      s1 += p[t + 256];
    }
    float cm = fmaxf(counts[cls], 1.0f);
    float m0 = s0 / cm, m1 = s1 / cm;
    __shared__ float red[256];
    red[t] = m0 * m0 + m1 * m1;
    __syncthreads();
    for (int off = 128; off > 0; off >>= 1) {
      if (t < off) red[t] += red[t + off];
      __syncthreads();
    }
    float inv = 1.0f / fmaxf(sqrtf(red[0]), EPSN);
    cent[(size_t)cls * DIMS + t] = m0 * inv;
    cent[(size_t)cls * DIMS + t + 256] = m1 * inv;
  }
}

// K3: nearest-centroid argmin (lexicographic ties = jnp.argmin).
__global__ void __launch_bounds__(256) knearest(const float* __restrict__ cent,
                                                const float* __restrict__ counts,
                                                int* __restrict__ nearest) {
  int i = blockIdx.x, j = threadIdx.x;
  __shared__ float ci[DIMS];
  ci[j] = cent[(size_t)i * DIMS + j];
  ci[j + 256] = cent[(size_t)i * DIMS + j + 256];
  __syncthreads();
  const float4* cj = reinterpret_cast<const float4*>(cent + (size_t)j * DIMS);
  float dot = 0.0f;
#pragma unroll 8
  for (int k = 0; k < DIMS / 4; ++k) {
    float4 v = cj[k];
    dot += v.x * ci[4*k] + v.y * ci[4*k+1] + v.z * ci[4*k+2] + v.w * ci[4*k+3];
  }
  float dist = sqrtf(fmaxf(2.0f - 2.0f * dot, 0.0f));
  bool valid = (j != i) && (counts[j] > 0.0f);
  float dv = valid ? dist : INFINITY;
  __shared__ float sd[256];
  __shared__ int si[256];
  sd[j] = dv; si[j] = j;
  __syncthreads();
  for (int off = 128; off > 0; off >>= 1) {
    if (j < off) {
      float o = sd[j + off]; int oi = si[j + off];
      if (o < sd[j] || (o == sd[j] && oi < si[j])) { sd[j] = o; si[j] = oi; }
    }
    __syncthreads();
  }
  if (j == 0) nearest[i] = si[0];
}

// K4: triplet terms; the LAST of all 2048 blocks computes the final
// present-masked mean inline (deterministic values).
__global__ void __launch_bounds__(256) kterm3(const float* __restrict__ emb,
                                              const float* __restrict__ invnorm,
                                              const int* __restrict__ rowidx,
                                              const int* __restrict__ bases,
                                              const float* __restrict__ counts,
                                              const float* __restrict__ cent,
                                              const int* __restrict__ nearest,
                                              float* __restrict__ tsums,
                                              int* __restrict__ tcnt,
                                              float* __restrict__ out) {
  int cls = blockIdx.x >> 3;  // TSPL == 8
  int sp = blockIdx.x & (TSPL - 1);
  int t = threadIdx.x, w = t >> 6, lane = t & 63;
  int base = bases[cls];
  int cnt = (int)counts[cls];
  int ng = nearest[cls];
  int cq = lane * 2;
  const float4* pp = reinterpret_cast<const float4*>(cent + (size_t)cls * DIMS) + cq;
  const float4* pn = reinterpret_cast<const float4*>(cent + (size_t)ng * DIMS) + cq;
  float4 P0 = pp[0], P1 = pp[1], N0 = pn[0], N1 = pn[1];
  float4 d0 = make_float4(N0.x - P0.x, N0.y - P0.y, N0.z - P0.z, N0.w - P0.w);
  float4 d1 = make_float4(N1.x - P1.x, N1.y - P1.y, N1.z - P1.z, N1.w - P1.w);
  int i0 = (cnt * sp) / TSPL;
  int i1 = (cnt * (sp + 1)) / TSPL;
  int n = i1 - i0;
  int j0 = i0 + ((n * w) >> 2);
  int j1 = i0 + ((n * (w + 1)) >> 2);
  const float4* ebase = reinterpret_cast<const float4*>(emb);
  float tsum = 0.0f;
  int j = j0;
  for (; j + 4 <= j1; j += 4) {
    int r[4];
#pragma unroll
    for (int k = 0; k < 4; ++k) r[k] = rowidx[base + j + k];
    float inv[4];
#pragma unroll
    for (int k = 0; k < 4; ++k) inv[k] = invnorm[r[k]];
    float4 a[4], b[4];
#pragma unroll
    for (int k = 0; k < 4; ++k) {
      const float4* p = ebase + (size_t)r[k] * (DIMS / 4) + cq;
      a[k] = p[0];
      b[k] = p[1];
    }
    float s[4];
#pragma unroll
    for (int k = 0; k < 4; ++k)
      s[k] = a[k].x*d0.x + a[k].y*d0.y + a[k].z*d0.z + a[k].w*d0.w
           + b[k].x*d1.x + b[k].y*d1.y + b[k].z*d1.z + b[k].w*d1.w;
#pragma unroll
    for (int off = 1; off < 64; off <<= 1) {
#pragma unroll
      for (int k = 0; k < 4; ++k) s[k] += __shfl_xor(s[k], off, 64);
    }
#pragma unroll
    for (int k = 0; k < 4; ++k) tsum += fmaxf(s[k] * inv[k] + MARGIN, 0.0f);
  }
  for (; j < j1; ++j) {
    int r0 = rowidx[base + j];
    float inv0 = invnorm[r0];
    const float4* p = ebase + (size_t)r0 * (DIMS / 4) + cq;
    float4 a = p[0], b = p[1];
    float s = a.x*d0.x + a.y*d0.y + a.z*d0.z + a.w*d0.w
            + b.x*d1.x + b.y*d1.y + b.z*d1.z + b.w*d1.w;
#pragma unroll
    for (int off = 1; off < 64; off <<= 1) s += __shfl_xor(s, off, 64);
    tsum += fmaxf(s * inv0 + MARGIN, 0.0f);
  }
  __shared__ float sred[4];
  if (lane == 0) sred[w] = tsum;
  __syncthreads();
  if (t == 0) tsums[blockIdx.x] = sred[0] + sred[1] + sred[2] + sred[3];
  // ---- last of all blocks: inline final reduction ----
  __threadfence();                       // release tsums
  __shared__ int lastf;
  if (t == 0) lastf = (atomicAdd(tcnt, 1) == NCLS * TSPL - 1) ? 1 : 0;
  __syncthreads();
  if (lastf) {
    __threadfence();                     // acquire all tsums
    float cntc = counts[t];
    bool present = cntc > 0.0f;
    float ls = 0.0f;
#pragma unroll
    for (int k = 0; k < TSPL; ++k) ls += tsums[t * TSPL + k];
    float v = present ? ls / fmaxf(cntc, 1.0f) : 0.0f;
    float np = present ? 1.0f : 0.0f;
    __shared__ float sv[256], spv[256];
    sv[t] = v; spv[t] = np;
    __syncthreads();
    for (int off = 128; off > 0; off >>= 1) {
      if (t < off) { sv[t] += sv[t + off]; spv[t] += spv[t + off]; }
      __syncthreads();
    }
    if (t == 0) out[0] = sv[0] / fmaxf(spv[0], 1.0f);
  }
}

extern "C" void kernel_launch(void* const* d_in, const int* in_sizes, int n_in,
                              void* d_out, int out_size, void* d_ws, size_t ws_size,
                              hipStream_t stream) {
  const float* emb = (const float*)d_in[0];
  const int* labels = (const int*)d_in[1];
  float* out = (float*)d_out;

  char* ws = (char*)d_ws;
  size_t off = 0;
  auto alloc = [&](size_t bytes) {
    char* p = ws + off;
    off += (bytes + 255) & ~(size_t)255;
    return p;
  };
  // sync counters first (single small contiguous memset region)
  int*   done    = (int*)alloc((size_t)(2 + NCLS) * 4);               // done, tcnt, ccnt[256]
  int*   tcnt    = done + 1;
  int*   ccnt    = done + 2;
  int*   hist    = (int*)alloc((size_t)NSTRIP * NCLS * 4);            // 64 KB
  int*   bases   = (int*)alloc((size_t)NCLS * 4);
  float* counts  = (float*)alloc((size_t)NCLS * 4);
  int*   nearest = (int*)alloc((size_t)NCLS * 4);
  int*   rowidx  = (int*)alloc((size_t)BROWS * 4);                    // 256 KB
  float* invnorm = (float*)alloc((size_t)BROWS * 4);                  // 256 KB
  float* tsums   = (float*)alloc((size_t)NCLS * TSPL * 4);            // 8 KB
  float* cent    = (float*)alloc((size_t)NCLS * DIMS * 4);            // 512 KB
  float* partials= (float*)alloc(((size_t)NCLS * DIMS * 4) << LSPL);  // 4 MB

  hipMemsetAsync(done, 0, (size_t)(2 + NCLS) * 4, stream);

  kscatter3<<<NSTRIP, 256, 0, stream>>>(labels, hist, done, bases, counts, rowidx);
  ksumn2<<<NCLS << LSPL, 256, 0, stream>>>(emb, rowidx, bases, counts, invnorm,
                                           partials, ccnt, cent);
  knearest<<<NCLS, 256, 0, stream>>>(cent, counts, nearest);
  kterm3<<<NCLS * TSPL, 256, 0, stream>>>(emb, invnorm, rowidx, bases, counts,
                                          cent, nearest, tsums, tcnt, out);
}

// Round 13
// 248.807 us; speedup vs baseline: 4.1781x; 3.6278x over previous
//
#include <hip/hip_runtime.h>
#include <math.h>

#define BROWS 65536
#define DIMS 512
#define NCLS 256
#define MARGIN 0.3f
#define EPSN 1e-12f
#define NSTRIP 64      // 64 strips x 1024 rows
#define SROWS 1024
#define LSPL 3         // 8 splits/class in ksumn
#define TSPL 8         // 8 splits/class in kterm2

// K1: per-strip label histogram (LDS atomics only).
__global__ void __launch_bounds__(256) khist2(const int* __restrict__ labels,
                                              int* __restrict__ hist) {
  __shared__ int h[NCLS];
  int t = threadIdx.x, s = blockIdx.x;
  h[t] = 0;
  __syncthreads();
  int base = s * SROWS + t;
#pragma unroll
  for (int k = 0; k < SROWS / 256; ++k) atomicAdd(&h[labels[base + k * 256]], 1);
  __syncthreads();
  hist[s * NCLS + t] = h[t];
}

// K2: per-strip deterministic scatter. Each strip block recomputes class bases
// (scan over all-strip totals) + its own strip prefix from hist; rows scatter
// via LDS cursors. Block 0 also publishes bases + float counts.
__global__ void __launch_bounds__(256) kscatter2(const int* __restrict__ labels,
                                                 const int* __restrict__ hist,
                                                 int* __restrict__ bases,
                                                 float* __restrict__ counts,
                                                 int* __restrict__ rowidx) {
  int t = threadIdx.x, s = blockIdx.x;  // t = class
  int run = 0, myoff = 0;
  for (int s2 = 0; s2 < NSTRIP; ++s2) {
    int h = hist[s2 * NCLS + t];        // coalesced across t
    if (s2 < s) myoff += h;
    run += h;
  }
  // exclusive scan of class totals
  __shared__ int sc[NCLS];
  sc[t] = run;
  __syncthreads();
  int v = sc[t];
  for (int off = 1; off < NCLS; off <<= 1) {
    int add = (t >= off) ? sc[t - off] : 0;
    __syncthreads();
    sc[t] = v = v + add;
    __syncthreads();
  }
  int excl = (t == 0) ? 0 : sc[t - 1];
  if (s == 0) {
    bases[t] = excl;
    counts[t] = (float)run;
  }
  __shared__ int loff[NCLS];
  __shared__ int cur[NCLS];
  loff[t] = excl + myoff;
  cur[t] = 0;
  __syncthreads();
  int rbase = s * SROWS + t;
#pragma unroll
  for (int k = 0; k < SROWS / 256; ++k) {
    int r = rbase + k * 256;
    int lab = labels[r];
    int lpos = atomicAdd(&cur[lab], 1);
    rowidx[loff[lab] + lpos] = r;
  }
}

// K3: fused row-norm + per-class segment sum of normalized rows. Wave holds
// the 512-dim partial in 8 VGPRs/lane; 4-row unroll keeps 8 independent
// dwordx4 loads in flight.
__global__ void __launch_bounds__(256) ksumn(const float* __restrict__ emb,
                                             const int* __restrict__ rowidx,
                                             const int* __restrict__ bases,
                                             const float* __restrict__ counts,
                                             float* __restrict__ invnorm,
                                             float* __restrict__ partials) {
  int cls = blockIdx.x >> LSPL;
  int sp = blockIdx.x & ((1 << LSPL) - 1);
  int t = threadIdx.x, w = t >> 6, lane = t & 63;
  int base = bases[cls];
  int cnt = (int)counts[cls];
  int i0 = (cnt * sp) >> LSPL;
  int i1 = (cnt * (sp + 1)) >> LSPL;
  int n = i1 - i0;
  int j0 = i0 + ((n * w) >> 2);
  int j1 = i0 + ((n * (w + 1)) >> 2);
  const float4* ebase = reinterpret_cast<const float4*>(emb);
  int cq = lane * 2;  // float4 index: cols [lane*8, lane*8+8)
  float4 acc0 = make_float4(0.f, 0.f, 0.f, 0.f);
  float4 acc1 = make_float4(0.f, 0.f, 0.f, 0.f);
  int j = j0;
  for (; j + 4 <= j1; j += 4) {
    int r[4];
#pragma unroll
    for (int k = 0; k < 4; ++k) r[k] = rowidx[base + j + k];
    float4 a[4], b[4];
#pragma unroll
    for (int k = 0; k < 4; ++k) {
      const float4* p = ebase + (size_t)r[k] * (DIMS / 4) + cq;
      a[k] = p[0];
      b[k] = p[1];
    }
    float s[4];
#pragma unroll
    for (int k = 0; k < 4; ++k)
      s[k] = a[k].x*a[k].x + a[k].y*a[k].y + a[k].z*a[k].z + a[k].w*a[k].w
           + b[k].x*b[k].x + b[k].y*b[k].y + b[k].z*b[k].z + b[k].w*b[k].w;
#pragma unroll
    for (int off = 1; off < 64; off <<= 1) {
#pragma unroll
      for (int k = 0; k < 4; ++k) s[k] += __shfl_xor(s[k], off, 64);
    }
    float q[4];
#pragma unroll
    for (int k = 0; k < 4; ++k) q[k] = 1.0f / fmaxf(sqrtf(s[k]), EPSN);
    if (lane == 0) {
      invnorm[r[0]] = q[0]; invnorm[r[1]] = q[1];
      invnorm[r[2]] = q[2]; invnorm[r[3]] = q[3];
    }
#pragma unroll
    for (int k = 0; k < 4; ++k) {
      acc0.x += a[k].x * q[k]; acc0.y += a[k].y * q[k];
      acc0.z += a[k].z * q[k]; acc0.w += a[k].w * q[k];
      acc1.x += b[k].x * q[k]; acc1.y += b[k].y * q[k];
      acc1.z += b[k].z * q[k]; acc1.w += b[k].w * q[k];
    }
  }
  for (; j < j1; ++j) {
    int r0 = rowidx[base + j];
    const float4* p = ebase + (size_t)r0 * (DIMS / 4) + cq;
    float4 a = p[0], b = p[1];
    float s = a.x*a.x + a.y*a.y + a.z*a.z + a.w*a.w
            + b.x*b.x + b.y*b.y + b.z*b.z + b.w*b.w;
#pragma unroll
    for (int off = 1; off < 64; off <<= 1) s += __shfl_xor(s, off, 64);
    float q0 = 1.0f / fmaxf(sqrtf(s), EPSN);
    if (lane == 0) invnorm[r0] = q0;
    acc0.x += a.x * q0; acc0.y += a.y * q0; acc0.z += a.z * q0; acc0.w += a.w * q0;
    acc1.x += b.x * q0; acc1.y += b.y * q0; acc1.z += b.z * q0; acc1.w += b.w * q0;
  }
  __shared__ float lds[4][DIMS];
  *reinterpret_cast<float4*>(&lds[w][lane * 8]) = acc0;
  *reinterpret_cast<float4*>(&lds[w][lane * 8 + 4]) = acc1;
  __syncthreads();
  float o0 = lds[0][t] + lds[1][t] + lds[2][t] + lds[3][t];
  float o1 = lds[0][t + 256] + lds[1][t + 256] + lds[2][t + 256] + lds[3][t + 256];
  float* outp = partials + ((size_t)sp * NCLS + cls) * DIMS;
  outp[t] = o0;
  outp[t + 256] = o1;
}

// K4: reduce split partials -> mean -> L2-normalized centroid.
__global__ void __launch_bounds__(256) kcent(const float* __restrict__ partials,
                                             const float* __restrict__ counts,
                                             float* __restrict__ cent) {
  int cls = blockIdx.x, t = threadIdx.x;
  float s0 = 0.0f, s1 = 0.0f;
#pragma unroll
  for (int sp = 0; sp < (1 << LSPL); ++sp) {
    const float* p = partials + ((size_t)sp * NCLS + cls) * DIMS;
    s0 += p[t];
    s1 += p[t + 256];
  }
  float cm = fmaxf(counts[cls], 1.0f);
  float m0 = s0 / cm, m1 = s1 / cm;
  __shared__ float red[256];
  red[t] = m0 * m0 + m1 * m1;
  __syncthreads();
  for (int off = 128; off > 0; off >>= 1) {
    if (t < off) red[t] += red[t + off];
    __syncthreads();
  }
  float inv = 1.0f / fmaxf(sqrtf(red[0]), EPSN);
  cent[(size_t)cls * DIMS + t] = m0 * inv;
  cent[(size_t)cls * DIMS + t + 256] = m1 * inv;
}

// K5: nearest-centroid argmin (lexicographic ties = jnp.argmin).
__global__ void __launch_bounds__(256) knearest(const float* __restrict__ cent,
                                                const float* __restrict__ counts,
                                                int* __restrict__ nearest) {
  int i = blockIdx.x, j = threadIdx.x;
  __shared__ float ci[DIMS];
  ci[j] = cent[(size_t)i * DIMS + j];
  ci[j + 256] = cent[(size_t)i * DIMS + j + 256];
  __syncthreads();
  const float4* cj = reinterpret_cast<const float4*>(cent + (size_t)j * DIMS);
  float dot = 0.0f;
#pragma unroll 8
  for (int k = 0; k < DIMS / 4; ++k) {
    float4 v = cj[k];
    dot += v.x * ci[4*k] + v.y * ci[4*k+1] + v.z * ci[4*k+2] + v.w * ci[4*k+3];
  }
  float dist = sqrtf(fmaxf(2.0f - 2.0f * dot, 0.0f));
  bool valid = (j != i) && (counts[j] > 0.0f);
  float dv = valid ? dist : INFINITY;
  __shared__ float sd[256];
  __shared__ int si[256];
  sd[j] = dv; si[j] = j;
  __syncthreads();
  for (int off = 128; off > 0; off >>= 1) {
    if (j < off) {
      float o = sd[j + off]; int oi = si[j + off];
      if (o < sd[j] || (o == sd[j] && oi < si[j])) { sd[j] = o; si[j] = oi; }
    }
    __syncthreads();
  }
  if (j == 0) nearest[i] = si[0];
}

// K6: triplet terms from f32 emb (L3-hot after ksumn).
// term = relu(dot(emb_row, neg_c - pos_c) * invnorm + margin).
// diff in registers (block-uniform class); 4-row unroll; no atomics.
__global__ void __launch_bounds__(256) kterm2(const float* __restrict__ emb,
                                              const float* __restrict__ invnorm,
                                              const int* __restrict__ rowidx,
                                              const int* __restrict__ bases,
                                              const float* __restrict__ counts,
                                              const float* __restrict__ cent,
                                              const int* __restrict__ nearest,
                                              float* __restrict__ tsums) {
  int cls = blockIdx.x >> 3;  // TSPL == 8
  int sp = blockIdx.x & (TSPL - 1);
  int t = threadIdx.x, w = t >> 6, lane = t & 63;
  int base = bases[cls];
  int cnt = (int)counts[cls];
  int ng = nearest[cls];
  int cq = lane * 2;
  const float4* pp = reinterpret_cast<const float4*>(cent + (size_t)cls * DIMS) + cq;
  const float4* pn = reinterpret_cast<const float4*>(cent + (size_t)ng * DIMS) + cq;
  float4 P0 = pp[0], P1 = pp[1], N0 = pn[0], N1 = pn[1];
  float4 d0 = make_float4(N0.x - P0.x, N0.y - P0.y, N0.z - P0.z, N0.w - P0.w);
  float4 d1 = make_float4(N1.x - P1.x, N1.y - P1.y, N1.z - P1.z, N1.w - P1.w);
  int i0 = (cnt * sp) / TSPL;
  int i1 = (cnt * (sp + 1)) / TSPL;
  int n = i1 - i0;
  int j0 = i0 + ((n * w) >> 2);
  int j1 = i0 + ((n * (w + 1)) >> 2);
  const float4* ebase = reinterpret_cast<const float4*>(emb);
  float tsum = 0.0f;
  int j = j0;
  for (; j + 4 <= j1; j += 4) {
    int r[4];
#pragma unroll
    for (int k = 0; k < 4; ++k) r[k] = rowidx[base + j + k];
    float inv[4];
#pragma unroll
    for (int k = 0; k < 4; ++k) inv[k] = invnorm[r[k]];
    float4 a[4], b[4];
#pragma unroll
    for (int k = 0; k < 4; ++k) {
      const float4* p = ebase + (size_t)r[k] * (DIMS / 4) + cq;
      a[k] = p[0];
      b[k] = p[1];
    }
    float s[4];
#pragma unroll
    for (int k = 0; k < 4; ++k)
      s[k] = a[k].x*d0.x + a[k].y*d0.y + a[k].z*d0.z + a[k].w*d0.w
           + b[k].x*d1.x + b[k].y*d1.y + b[k].z*d1.z + b[k].w*d1.w;
#pragma unroll
    for (int off = 1; off < 64; off <<= 1) {
#pragma unroll
      for (int k = 0; k < 4; ++k) s[k] += __shfl_xor(s[k], off, 64);
    }
#pragma unroll
    for (int k = 0; k < 4; ++k) tsum += fmaxf(s[k] * inv[k] + MARGIN, 0.0f);
  }
  for (; j < j1; ++j) {
    int r0 = rowidx[base + j];
    float inv0 = invnorm[r0];
    const float4* p = ebase + (size_t)r0 * (DIMS / 4) + cq;
    float4 a = p[0], b = p[1];
    float s = a.x*d0.x + a.y*d0.y + a.z*d0.z + a.w*d0.w
            + b.x*d1.x + b.y*d1.y + b.z*d1.z + b.w*d1.w;
#pragma unroll
    for (int off = 1; off < 64; off <<= 1) s += __shfl_xor(s, off, 64);
    tsum += fmaxf(s * inv0 + MARGIN, 0.0f);
  }
  __shared__ float sred[4];
  if (lane == 0) sred[w] = tsum;
  __syncthreads();
  if (t == 0) tsums[blockIdx.x] = sred[0] + sred[1] + sred[2] + sred[3];
}

// K7: final present-masked mean of per-class means.
__global__ void __launch_bounds__(256) kfinal(const float* __restrict__ counts,
                                              const float* __restrict__ tsums,
                                              float* __restrict__ out) {
  int t = threadIdx.x;
  float cnt = counts[t];
  bool present = cnt > 0.0f;
  float ls = 0.0f;
#pragma unroll
  for (int k = 0; k < TSPL; ++k) ls += tsums[t * TSPL + k];
  float v = present ? ls / fmaxf(cnt, 1.0f) : 0.0f;
  float np = present ? 1.0f : 0.0f;
  __shared__ float sv[256], sp[256];
  sv[t] = v; sp[t] = np;
  __syncthreads();
  for (int off = 128; off > 0; off >>= 1) {
    if (t < off) { sv[t] += sv[t + off]; sp[t] += sp[t + off]; }
    __syncthreads();
  }
  if (t == 0) out[0] = sv[0] / fmaxf(sp[0], 1.0f);
}

extern "C" void kernel_launch(void* const* d_in, const int* in_sizes, int n_in,
                              void* d_out, int out_size, void* d_ws, size_t ws_size,
                              hipStream_t stream) {
  const float* emb = (const float*)d_in[0];
  const int* labels = (const int*)d_in[1];
  float* out = (float*)d_out;

  char* ws = (char*)d_ws;
  size_t off = 0;
  auto alloc = [&](size_t bytes) {
    char* p = ws + off;
    off += (bytes + 255) & ~(size_t)255;
    return p;
  };
  int*   hist    = (int*)alloc((size_t)NSTRIP * NCLS * 4);            // 64 KB
  int*   bases   = (int*)alloc((size_t)NCLS * 4);                     // 1 KB
  float* counts  = (float*)alloc((size_t)NCLS * 4);                   // 1 KB
  float* cent    = (float*)alloc((size_t)NCLS * DIMS * 4);            // 512 KB
  int*   nearest = (int*)alloc((size_t)NCLS * 4);                     // 1 KB
  int*   rowidx  = (int*)alloc((size_t)BROWS * 4);                    // 256 KB
  float* invnorm = (float*)alloc((size_t)BROWS * 4);                  // 256 KB
  float* tsums   = (float*)alloc((size_t)NCLS * TSPL * 4);            // 8 KB
  float* partials= (float*)alloc(((size_t)NCLS * DIMS * 4) << LSPL);  // 4 MB

  khist2<<<NSTRIP, 256, 0, stream>>>(labels, hist);
  kscatter2<<<NSTRIP, 256, 0, stream>>>(labels, hist, bases, counts, rowidx);
  ksumn<<<NCLS << LSPL, 256, 0, stream>>>(emb, rowidx, bases, counts, invnorm, partials);
  kcent<<<NCLS, 256, 0, stream>>>(partials, counts, cent);
  knearest<<<NCLS, 256, 0, stream>>>(cent, counts, nearest);
  kterm2<<<NCLS * TSPL, 256, 0, stream>>>(emb, invnorm, rowidx, bases, counts,
                                          cent, nearest, tsums);
  kfinal<<<1, 256, 0, stream>>>(counts, tsums, out);
}